// Round 1
// baseline (303.412 us; speedup 1.0000x reference)
//
#include <hip/hip_runtime.h>

// ---------------------------------------------------------------------------
// CrossAttention_LocalAVTokens: bs=32, nmm=256, nv=196, na=60 (nv+na=256),
// DIM=768, HEADS=12, hd=64. Outputs: out [32,256,768] f32, attn [32,12,256,256] f32.
// fp16 MFMA 16x16x32, fp32 accumulate.
// Round 3: (1) 2-phase double-buffered GEMM K-loop (T3-minimum: stage next tile
// before computing current, single raw barrier + vmcnt(0) per tile — load
// latency hidden under MFMA instead of drained at every __syncthreads);
// (2) attn: pre-PV barrier is lgkmcnt-only so the 100 MB attn-prob store
// overlaps PV MFMA instead of draining at the barrier; (3) prep kernels merged.
// ---------------------------------------------------------------------------

typedef __attribute__((ext_vector_type(8))) _Float16 f16x8;
typedef __attribute__((ext_vector_type(4))) _Float16 f16x4;
typedef __attribute__((ext_vector_type(4))) float    f32x4;

#define AS1 __attribute__((address_space(1)))
#define AS3 __attribute__((address_space(3)))

__device__ __forceinline__ void gload_lds16(const void* g, void* l) {
    void* gnc = const_cast<void*>(g);
    __builtin_amdgcn_global_load_lds((AS1 void*)gnc, (AS3 void*)l, 16, 0, 0);
}

// ---------------------------------------------------------------------------
// prep_all: merged activation cast/concat + weight transpose/cast.
// blocks [0,12288): acts (float4 granularity). blocks [12288,21504): weights.
// ---------------------------------------------------------------------------
__global__ __launch_bounds__(256) void prep_all(const float* __restrict__ xmm,
                                                const float* __restrict__ xv,
                                                const float* __restrict__ xa,
                                                const float* __restrict__ Wq,
                                                const float* __restrict__ Wkv,
                                                const float* __restrict__ Wproj,
                                                _Float16* __restrict__ xmm16,
                                                _Float16* __restrict__ xsrc16,
                                                _Float16* __restrict__ WqT,
                                                _Float16* __restrict__ WkvT,
                                                _Float16* __restrict__ WprojT) {
    int bid = blockIdx.x;
    if (bid < 12288) {
        int id = bid * 256 + threadIdx.x;         // 2 * 1572864 float4s
        float4 v;
        _Float16* dst;
        int off;
        if (id < 1572864) {
            v = ((const float4*)xmm)[id];
            dst = xmm16; off = id;
        } else {
            int t = id - 1572864;
            int c4 = t % 192;
            int r  = (t / 192) & 255;
            int b  = t / 49152;
            if (r < 196) v = ((const float4*)xv)[((long)b * 196 + r) * 192 + c4];
            else         v = ((const float4*)xa)[((long)b * 60 + (r - 196)) * 192 + c4];
            dst = xsrc16; off = t;
        }
        f16x4 h = { (_Float16)v.x, (_Float16)v.y, (_Float16)v.z, (_Float16)v.w };
        ((f16x4*)dst)[off] = h;
        return;
    }
    int id = (bid - 12288) * 256 + threadIdx.x;
    if (id < 589824) {            // WqT [768n][768k] = 0.125 * Wq[k][n]
        int k = id % 768, n = id / 768;
        WqT[id] = (_Float16)(0.125f * Wq[(long)k * 768 + n]);
        return;
    }
    id -= 589824;
    if (id < 1179648) {           // WkvT [1536n][768k]
        int k = id % 768, n = id / 768;
        WkvT[id] = (_Float16)Wkv[(long)k * 1536 + n];
        return;
    }
    id -= 1179648;
    if (id < 589824) {            // WprojT [768n][768k]
        int k = id % 768, n = id / 768;
        WprojT[id] = (_Float16)Wproj[(long)k * 768 + n];
    }
}

// ---------------------------------------------------------------------------
// Shared GEMM body: C[M,N] = A[M,K] @ Bt[N,K]^T, 128x128 tile, BK=64, 4 waves.
// 2-phase double-buffered pipeline: stage(buf^1, kt+1) issued BEFORE compute(buf),
// then s_waitcnt vmcnt(0) lgkmcnt(0) + raw s_barrier — one barrier per K-step,
// global_load_lds latency hidden under ds_read+MFMA of the current tile.
// mfma(bf, af) => lane holds C[row][col0..col0+3] -> vector stores.
// ---------------------------------------------------------------------------
template <int OUT_F32>
__device__ __forceinline__ void gemm_body(const _Float16* __restrict__ A,
                                          const _Float16* __restrict__ Bt,
                                          void* __restrict__ C,
                                          const float* __restrict__ bias,
                                          long bm, long bn, int N, int K) {
    __shared__ _Float16 As[2][128 * 64];      // 64 KB total with Bs -> 2 blocks/CU
    __shared__ _Float16 Bs[2][128 * 64];

    const int tid  = threadIdx.x;
    const int wave = tid >> 6, lane = tid & 63;
    const int lrow = lane & 15, quad = lane >> 4;
    const int wm = (wave >> 1) * 64, wn = (wave & 1) * 64;

    f32x4 acc[4][4];
    const f32x4 fz = {0.f, 0.f, 0.f, 0.f};
#pragma unroll
    for (int mt = 0; mt < 4; ++mt)
#pragma unroll
        for (int nt = 0; nt < 4; ++nt) acc[mt][nt] = fz;

    auto stage = [&](int buf, int k0) {
#pragma unroll
        for (int it = 0; it < 4; ++it) {
            int seg = tid + it * 256;                 // 1024 segs of 8 halves
            int rr = seg >> 3, pp = seg & 7;
            int cc = ((pp ^ (rr & 7)) << 3);          // swizzled source column
            gload_lds16(A  + (bm + rr) * (long)K + k0 + cc, &As[buf][seg * 8]);
            gload_lds16(Bt + (bn + rr) * (long)K + k0 + cc, &Bs[buf][seg * 8]);
        }
    };

    auto compute = [&](int buf) {
#pragma unroll
        for (int ks = 0; ks < 2; ++ks) {
            f16x8 af[4], bf[4];
#pragma unroll
            for (int mt = 0; mt < 4; ++mt) {
                int r = wm + mt * 16 + lrow;
                af[mt] = *(const f16x8*)(&As[buf][r * 64 + (((ks * 4 + quad) ^ (r & 7)) << 3)]);
            }
#pragma unroll
            for (int nt = 0; nt < 4; ++nt) {
                int r = wn + nt * 16 + lrow;
                bf[nt] = *(const f16x8*)(&Bs[buf][r * 64 + (((ks * 4 + quad) ^ (r & 7)) << 3)]);
            }
#pragma unroll
            for (int mt = 0; mt < 4; ++mt)
#pragma unroll
                for (int nt = 0; nt < 4; ++nt)
                    acc[mt][nt] = __builtin_amdgcn_mfma_f32_16x16x32_f16(
                        bf[nt], af[mt], acc[mt][nt], 0, 0, 0);   // swapped: C^T tile
        }
    };

    const int KT = K >> 6;                    // 12 for K=768
    stage(0, 0);
    asm volatile("s_waitcnt vmcnt(0)" ::: "memory");
    __builtin_amdgcn_s_barrier();

    for (int kt = 0; kt < KT; kt += 2) {
        // phase A: compute buf0, prefetch tile kt+1 into buf1
        if (kt + 1 < KT) stage(1, (kt + 1) << 6);
        compute(0);
        asm volatile("s_waitcnt vmcnt(0) lgkmcnt(0)" ::: "memory");
        __builtin_amdgcn_sched_barrier(0);
        __builtin_amdgcn_s_barrier();
        // phase B: compute buf1, prefetch tile kt+2 into buf0
        if (kt + 1 < KT) {
            if (kt + 2 < KT) stage(0, (kt + 2) << 6);
            compute(1);
            asm volatile("s_waitcnt vmcnt(0) lgkmcnt(0)" ::: "memory");
            __builtin_amdgcn_sched_barrier(0);
            __builtin_amdgcn_s_barrier();
        }
    }

    // epilogue: lane owns C[bm+wm+mt*16+lrow][bn+wn+nt*16+quad*4 + 0..3]
#pragma unroll
    for (int mt = 0; mt < 4; ++mt) {
        long row = bm + wm + mt * 16 + lrow;
#pragma unroll
        for (int nt = 0; nt < 4; ++nt) {
            long col0 = bn + wn + nt * 16 + quad * 4;
            if (OUT_F32) {
                float4 b4 = *(const float4*)(bias + col0);
                float4 o = { acc[mt][nt][0] + b4.x, acc[mt][nt][1] + b4.y,
                             acc[mt][nt][2] + b4.z, acc[mt][nt][3] + b4.w };
                *(float4*)((float*)C + row * N + col0) = o;
            } else {
                f16x4 h = { (_Float16)acc[mt][nt][0], (_Float16)acc[mt][nt][1],
                            (_Float16)acc[mt][nt][2], (_Float16)acc[mt][nt][3] };
                *(f16x4*)((_Float16*)C + row * N + col0) = h;
            }
        }
    }
}

// Merged Q + KV projection: grid (6+12, 64). bx<6 -> Q, else KV.
__global__ __launch_bounds__(256, 2)
void gemm_qkv(const _Float16* __restrict__ xmm16, const _Float16* __restrict__ xsrc16,
              const _Float16* __restrict__ WqT, const _Float16* __restrict__ WkvT,
              _Float16* __restrict__ Q16, _Float16* __restrict__ KV16) {
    const int bx = blockIdx.x;
    const long bm = (long)blockIdx.y * 128;
    if (bx < 6) gemm_body<0>(xmm16,  WqT,  (void*)Q16,  nullptr, bm, (long)bx * 128,       768,  768);
    else        gemm_body<0>(xsrc16, WkvT, (void*)KV16, nullptr, bm, (long)(bx - 6) * 128, 1536, 768);
}

// Output projection (+bias), f32 out. grid (6, 64).
__global__ __launch_bounds__(256, 2)
void gemm_proj(const _Float16* __restrict__ O16, const _Float16* __restrict__ WprojT,
               float* __restrict__ out, const float* __restrict__ bias) {
    gemm_body<1>(O16, WprojT, (void*)out, bias, (long)blockIdx.y * 128, (long)blockIdx.x * 128, 768, 768);
}

// ---------------------------------------------------------------------------
// Fused attention: WG = (qblock=64 q-rows, head, batch) = (4,12,32) grid.
// LDS: Ks[256][64] swz | Vt[64][256] swz; Ps[64][256] swz aliases Ks.
// S computed transposed (mfma(bk,aq)): lane holds q=wave*16+lrow fixed,
// keys nt*16+quad*4+{0..3} -> softmax needs only shfl_xor 16,32.
// Pre-PV barrier is lgkmcnt-only: the attn-prob f32 stores (64 KB/block,
// 100 MB total) stay in flight and overlap the PV MFMAs.
// ---------------------------------------------------------------------------
__global__ __launch_bounds__(256, 2)
void attn_kernel(const _Float16* __restrict__ Qg, const _Float16* __restrict__ KVg,
                 float* __restrict__ attn_out, _Float16* __restrict__ Og) {
    __shared__ _Float16 sh[32768];          // 64 KB
    _Float16* Ks = sh;
    _Float16* Vt = sh + 16384;
    _Float16* Ps = sh;                      // aliases Ks after S phase

    const int tid  = threadIdx.x;
    const int wave = tid >> 6, lane = tid & 63;
    const int lrow = lane & 15, quad = lane >> 4;
    const int qb = blockIdx.x, h = blockIdx.y, b = blockIdx.z;
    const long qrow0 = (long)b * 256 + qb * 64;
    const long krow0 = (long)b * 256;

    // Q fragments from global (A layout: idx=lane&15 -> q, k=quad*8+j)
    f16x8 aq[2];
#pragma unroll
    for (int ks = 0; ks < 2; ++ks)
        aq[ks] = *(const f16x8*)(Qg + (qrow0 + wave * 16 + lrow) * 768 + h * 64 + ks * 32 + quad * 8);

    // K -> LDS async, swizzled
#pragma unroll
    for (int it = 0; it < 8; ++it) {
        int seg = tid + it * 256;
        int rr = seg >> 3, pp = seg & 7;
        int cc = ((pp ^ (rr & 7)) << 3);
        gload_lds16(KVg + (krow0 + rr) * 1536 + h * 64 + cc, Ks + seg * 8);
    }
    // V -> LDS transposed (V^T[d][key]), swizzled 16B blocks
#pragma unroll
    for (int it = 0; it < 8; ++it) {
        int seg = tid + it * 256;
        int key = seg >> 3, d0 = (seg & 7) * 8;
        f16x8 v = *(const f16x8*)(KVg + (krow0 + key) * 1536 + 768 + h * 64 + d0);
#pragma unroll
        for (int i = 0; i < 8; ++i) {
            int d = d0 + i;
            Vt[d * 256 + ((((key >> 3) ^ (d & 7)) << 3) | (key & 7))] = v[i];
        }
    }
    __syncthreads();

    // S^T = K Q^T : sacc[nt] lane holds keys nt*16+quad*4+{0..3}, q=wave*16+lrow
    f32x4 sacc[16];
    const f32x4 fz = {0.f, 0.f, 0.f, 0.f};
#pragma unroll
    for (int nt = 0; nt < 16; ++nt) sacc[nt] = fz;
#pragma unroll
    for (int ks = 0; ks < 2; ++ks) {
#pragma unroll
        for (int nt = 0; nt < 16; ++nt) {
            int r = nt * 16 + lrow;
            f16x8 bk = *(const f16x8*)(Ks + r * 64 + (((ks * 4 + quad) ^ (r & 7)) << 3));
            sacc[nt] = __builtin_amdgcn_mfma_f32_16x16x32_f16(bk, aq[ks], sacc[nt], 0, 0, 0);
        }
    }

    // softmax over keys for q=wave*16+lrow: 64 in-lane + quads (shfl 16,32).
    // scale (0.125) already folded into Wq.
    float m = -1e30f;
#pragma unroll
    for (int nt = 0; nt < 16; ++nt)
#pragma unroll
        for (int j = 0; j < 4; ++j) m = fmaxf(m, sacc[nt][j]);
    m = fmaxf(m, __shfl_xor(m, 16));
    m = fmaxf(m, __shfl_xor(m, 32));
    float s = 0.f;
#pragma unroll
    for (int nt = 0; nt < 16; ++nt)
#pragma unroll
        for (int j = 0; j < 4; ++j) {
            float p = __expf(sacc[nt][j] - m);
            sacc[nt][j] = p; s += p;
        }
    s += __shfl_xor(s, 16);
    s += __shfl_xor(s, 32);
    const float li = 1.f / s;

    __syncthreads();   // all waves done reading Ks before Ps overwrites it

    // write attn (float4, stays in flight through PV) + stage normalized P (LDS)
    const long abase = (((long)b * 12 + h) * 256 + qb * 64) * 256;
    const int q = wave * 16 + lrow;
#pragma unroll
    for (int nt = 0; nt < 16; ++nt) {
        float4 o = { sacc[nt][0] * li, sacc[nt][1] * li, sacc[nt][2] * li, sacc[nt][3] * li };
        *(float4*)(attn_out + abase + (long)q * 256 + nt * 16 + quad * 4) = o;
        f16x4 hp = { (_Float16)o.x, (_Float16)o.y, (_Float16)o.z, (_Float16)o.w };
        int blk = nt * 2 + (quad >> 1);
        *(f16x4*)(Ps + q * 256 + ((blk ^ (q & 7)) << 3) + ((quad & 1) << 2)) = hp;
    }
    // Ps ds_writes must land (lgkmcnt), but do NOT drain the global stores (vmcnt)
    asm volatile("s_waitcnt lgkmcnt(0)" ::: "memory");
    __builtin_amdgcn_sched_barrier(0);
    __builtin_amdgcn_s_barrier();

    // O = P V : mfma(bv, ap) -> lane holds d=nt*16+quad*4+{0..3}, q=wave*16+lrow
    f32x4 oacc[4];
#pragma unroll
    for (int nt = 0; nt < 4; ++nt) oacc[nt] = fz;
#pragma unroll
    for (int ks = 0; ks < 8; ++ks) {
        int pr = wave * 16 + lrow;
        f16x8 ap = *(const f16x8*)(Ps + pr * 256 + (((ks * 4 + quad) ^ (pr & 7)) << 3));
#pragma unroll
        for (int nt = 0; nt < 4; ++nt) {
            int d = nt * 16 + lrow;
            f16x8 bv = *(const f16x8*)(Vt + d * 256 + (((ks * 4 + quad) ^ (d & 7)) << 3));
            oacc[nt] = __builtin_amdgcn_mfma_f32_16x16x32_f16(bv, ap, oacc[nt], 0, 0, 0);
        }
    }
#pragma unroll
    for (int nt = 0; nt < 4; ++nt) {
        f16x4 ho = { (_Float16)oacc[nt][0], (_Float16)oacc[nt][1],
                     (_Float16)oacc[nt][2], (_Float16)oacc[nt][3] };
        *(f16x4*)(Og + (qrow0 + wave * 16 + lrow) * 768 + h * 64 + nt * 16 + quad * 4) = ho;
    }
}

// ---------------------------------------------------------------------------
extern "C" void kernel_launch(void* const* d_in, const int* in_sizes, int n_in,
                              void* d_out, int out_size, void* d_ws, size_t ws_size,
                              hipStream_t stream) {
    const float* xmm   = (const float*)d_in[0];  // [32,256,768]
    const float* xv    = (const float*)d_in[1];  // [32,196,768]
    const float* xa    = (const float*)d_in[2];  // [32, 60,768]
    const float* Wq    = (const float*)d_in[3];  // [768,768]
    const float* Wkv   = (const float*)d_in[4];  // [768,1536]
    const float* Wproj = (const float*)d_in[5];  // [768,768]
    const float* bproj = (const float*)d_in[6];  // [768]

    float* out  = (float*)d_out;            // [32,256,768]
    float* attn = out + 6291456;            // [32,12,256,256]

    char* ws = (char*)d_ws;
    _Float16* xmm16  = (_Float16*)(ws);                   // 12,582,912 B
    _Float16* xsrc16 = (_Float16*)(ws + 12582912);        // 12,582,912 B
    _Float16* WqT    = (_Float16*)(ws + 25165824);        //  1,179,648 B
    _Float16* WkvT   = (_Float16*)(ws + 26345472);        //  2,359,296 B
    _Float16* WprojT = (_Float16*)(ws + 28704768);        //  1,179,648 B
    _Float16* Q16    = (_Float16*)(ws + 29884416);        // 12,582,912 B
    _Float16* KV16   = (_Float16*)(ws + 42467328);        // 25,165,824 B
    _Float16* O16    = xmm16;   // xmm16 dead after QKV GEMM; reuse for O

    prep_all<<<21504, 256, 0, stream>>>(xmm, xv, xa, Wq, Wkv, Wproj,
                                        xmm16, xsrc16, WqT, WkvT, WprojT);

    gemm_qkv<<<dim3(18, 64), 256, 0, stream>>>(xmm16, xsrc16, WqT, WkvT, Q16, KV16);

    attn_kernel<<<dim3(4, 12, 32), 256, 0, stream>>>(Q16, KV16, attn, O16);

    gemm_proj<<<dim3(6, 64), 256, 0, stream>>>(O16, WprojT, out, bproj);
}

// Round 4
// 271.304 us; speedup vs baseline: 1.1183x; 1.1183x over previous
//
#include <hip/hip_runtime.h>

// ---------------------------------------------------------------------------
// CrossAttention_LocalAVTokens: bs=32, nmm=256, nv=196, na=60 (nv+na=256),
// DIM=768, HEADS=12, hd=64. Outputs: out [32,256,768] f32, attn [32,12,256,256] f32.
// fp16 MFMA 16x16x32, fp32 accumulate.
// Round 6: round-4 feature set minus s_setprio (defensive removal — only
// construct never validated on this harness; isolating repeated container
// failure). Single-buffer GEMM, coalesced LDS-tile weight transpose,
// XCD-aware bijective block swizzles on all MFMA kernels.
// ---------------------------------------------------------------------------

typedef __attribute__((ext_vector_type(8))) _Float16 f16x8;
typedef __attribute__((ext_vector_type(4))) _Float16 f16x4;
typedef __attribute__((ext_vector_type(4))) float    f32x4;

#define AS1 __attribute__((address_space(1)))
#define AS3 __attribute__((address_space(3)))

__device__ __forceinline__ void gload_lds16(const void* g, void* l) {
    void* gnc = const_cast<void*>(g);
    __builtin_amdgcn_global_load_lds((AS1 void*)gnc, (AS3 void*)l, 16, 0, 0);
}

// ---------------------------------------------------------------------------
// prep_all: blocks [0,12288): activation cast/concat (float4 coalesced).
// blocks [12288,12864): weight transpose via 64x64 LDS tile — both the global
// read (rows of W) and the global write (rows of W^T) are coalesced.
// ---------------------------------------------------------------------------
__global__ __launch_bounds__(256) void prep_all(const float* __restrict__ xmm,
                                                const float* __restrict__ xv,
                                                const float* __restrict__ xa,
                                                const float* __restrict__ Wq,
                                                const float* __restrict__ Wkv,
                                                const float* __restrict__ Wproj,
                                                _Float16* __restrict__ xmm16,
                                                _Float16* __restrict__ xsrc16,
                                                _Float16* __restrict__ WqT,
                                                _Float16* __restrict__ WkvT,
                                                _Float16* __restrict__ WprojT) {
    __shared__ _Float16 wlds[64][72];       // [n_local][k_local], padded
    int bid = blockIdx.x;
    if (bid < 12288) {
        int id = bid * 256 + threadIdx.x;         // 2 * 1572864 float4s
        float4 v;
        _Float16* dst;
        int off;
        if (id < 1572864) {
            v = ((const float4*)xmm)[id];
            dst = xmm16; off = id;
        } else {
            int t = id - 1572864;
            int c4 = t % 192;
            int r  = (t / 192) & 255;
            int b  = t / 49152;
            if (r < 196) v = ((const float4*)xv)[((long)b * 196 + r) * 192 + c4];
            else         v = ((const float4*)xa)[((long)b * 60 + (r - 196)) * 192 + c4];
            dst = xsrc16; off = t;
        }
        f16x4 h = { (_Float16)v.x, (_Float16)v.y, (_Float16)v.z, (_Float16)v.w };
        ((f16x4*)dst)[off] = h;
        return;
    }
    // ---- weight transpose tiles: 144 (Wq) + 288 (Wkv) + 144 (Wproj) ----
    int t = bid - 12288;
    const float* src; _Float16* dst; int W; float scale; int tk, tn;
    if (t < 144)      { src = Wq;    dst = WqT;    W = 768;  scale = 0.125f; tk = t % 12;  tn = t / 12; }
    else if (t < 432) { int u = t - 144; src = Wkv;   dst = WkvT;   W = 1536; scale = 1.0f; tk = u % 12; tn = u / 12; }
    else              { int u = t - 432; src = Wproj; dst = WprojT; W = 768;  scale = 1.0f; tk = u % 12; tn = u / 12; }
    const int tk0 = tk * 64, tn0 = tn * 64;
    const int rloc = threadIdx.x >> 4, c0 = (threadIdx.x & 15) * 4;
#pragma unroll
    for (int i = 0; i < 4; ++i) {
        int k = tk0 + rloc + 16 * i;                 // coalesced read: row k, cols tn0+c0..+3
        float4 v = *(const float4*)(src + (long)k * W + tn0 + c0);
        wlds[c0 + 0][rloc + 16 * i] = (_Float16)(v.x * scale);
        wlds[c0 + 1][rloc + 16 * i] = (_Float16)(v.y * scale);
        wlds[c0 + 2][rloc + 16 * i] = (_Float16)(v.z * scale);
        wlds[c0 + 3][rloc + 16 * i] = (_Float16)(v.w * scale);
    }
    __syncthreads();
#pragma unroll
    for (int i = 0; i < 4; ++i) {
        int nloc = rloc + 16 * i;                    // coalesced write: row tn0+nloc of W^T
        f16x4 h = *(const f16x4*)(&wlds[nloc][c0]);
        *(f16x4*)(dst + (long)(tn0 + nloc) * 768 + tk0 + c0) = h;
    }
}

// ---------------------------------------------------------------------------
// Shared GEMM body: C[M,N] = A[M,K] @ Bt[N,K]^T, 128x128 tile, BK=64, 4 waves.
// Single-buffer (32 KB LDS -> 3+ blocks/CU; implicit wave-level overlap hides
// the stage latency — measured better than explicit dbuf at 64 KB).
// mfma(bf, af) => lane holds C[row][col0..col0+3] -> vector stores.
// ---------------------------------------------------------------------------
template <int OUT_F32>
__device__ __forceinline__ void gemm_body(const _Float16* __restrict__ A,
                                          const _Float16* __restrict__ Bt,
                                          void* __restrict__ C,
                                          const float* __restrict__ bias,
                                          long bm, long bn, int N, int K) {
    __shared__ _Float16 As[128 * 64];
    __shared__ _Float16 Bs[128 * 64];

    const int tid  = threadIdx.x;
    const int wave = tid >> 6, lane = tid & 63;
    const int lrow = lane & 15, quad = lane >> 4;
    const int wm = (wave >> 1) * 64, wn = (wave & 1) * 64;

    f32x4 acc[4][4];
    const f32x4 fz = {0.f, 0.f, 0.f, 0.f};
#pragma unroll
    for (int mt = 0; mt < 4; ++mt)
#pragma unroll
        for (int nt = 0; nt < 4; ++nt) acc[mt][nt] = fz;

    for (int k0 = 0; k0 < K; k0 += 64) {
#pragma unroll
        for (int it = 0; it < 4; ++it) {
            int seg = tid + it * 256;                 // 1024 segs of 8 halves
            int rr = seg >> 3, pp = seg & 7;
            int cc = ((pp ^ (rr & 7)) << 3);          // swizzled source column
            gload_lds16(A  + (bm + rr) * (long)K + k0 + cc, As + seg * 8);
            gload_lds16(Bt + (bn + rr) * (long)K + k0 + cc, Bs + seg * 8);
        }
        __syncthreads();
#pragma unroll
        for (int ks = 0; ks < 2; ++ks) {
            f16x8 af[4], bf[4];
#pragma unroll
            for (int mt = 0; mt < 4; ++mt) {
                int r = wm + mt * 16 + lrow;
                af[mt] = *(const f16x8*)(As + r * 64 + (((ks * 4 + quad) ^ (r & 7)) << 3));
            }
#pragma unroll
            for (int nt = 0; nt < 4; ++nt) {
                int r = wn + nt * 16 + lrow;
                bf[nt] = *(const f16x8*)(Bs + r * 64 + (((ks * 4 + quad) ^ (r & 7)) << 3));
            }
#pragma unroll
            for (int mt = 0; mt < 4; ++mt)
#pragma unroll
                for (int nt = 0; nt < 4; ++nt)
                    acc[mt][nt] = __builtin_amdgcn_mfma_f32_16x16x32_f16(
                        bf[nt], af[mt], acc[mt][nt], 0, 0, 0);   // swapped: C^T tile
        }
        __syncthreads();
    }

    // epilogue: lane owns C[bm+wm+mt*16+lrow][bn+wn+nt*16+quad*4 + 0..3]
#pragma unroll
    for (int mt = 0; mt < 4; ++mt) {
        long row = bm + wm + mt * 16 + lrow;
#pragma unroll
        for (int nt = 0; nt < 4; ++nt) {
            long col0 = bn + wn + nt * 16 + quad * 4;
            if (OUT_F32) {
                float4 b4 = *(const float4*)(bias + col0);
                float4 o = { acc[mt][nt][0] + b4.x, acc[mt][nt][1] + b4.y,
                             acc[mt][nt][2] + b4.z, acc[mt][nt][3] + b4.w };
                *(float4*)((float*)C + row * N + col0) = o;
            } else {
                f16x4 h = { (_Float16)acc[mt][nt][0], (_Float16)acc[mt][nt][1],
                            (_Float16)acc[mt][nt][2], (_Float16)acc[mt][nt][3] };
                *(f16x4*)((_Float16*)C + row * N + col0) = h;
            }
        }
    }
}

// Merged Q + KV projection, 1-D grid of 1152 blocks (= 8 XCDs * 144).
// Bijective XCD swizzle: each XCD gets 144 consecutive work items = 8 full
// M-panels — A-panels read once into that XCD's L2, weights L2-resident.
__global__ __launch_bounds__(256, 2)
void gemm_qkv(const _Float16* __restrict__ xmm16, const _Float16* __restrict__ xsrc16,
              const _Float16* __restrict__ WqT, const _Float16* __restrict__ WkvT,
              _Float16* __restrict__ Q16, _Float16* __restrict__ KV16) {
    const int f = blockIdx.x;
    const int w = ((f & 7) * 144) + (f >> 3);        // 1152 = 8*144, bijective
    const int bx = w % 18;
    const long bm = (long)(w / 18) * 128;
    if (bx < 6) gemm_body<0>(xmm16,  WqT,  (void*)Q16,  nullptr, bm, (long)bx * 128,       768,  768);
    else        gemm_body<0>(xsrc16, WkvT, (void*)KV16, nullptr, bm, (long)(bx - 6) * 128, 1536, 768);
}

// Output projection (+bias), f32 out. 1-D grid of 384 blocks (= 8 * 48).
__global__ __launch_bounds__(256, 2)
void gemm_proj(const _Float16* __restrict__ O16, const _Float16* __restrict__ WprojT,
               float* __restrict__ out, const float* __restrict__ bias) {
    const int f = blockIdx.x;
    const int w = ((f & 7) * 48) + (f >> 3);         // 384 = 8*48, bijective
    const int bx = w % 6;
    const long bm = (long)(w / 6) * 128;
    gemm_body<1>(O16, WprojT, (void*)out, bias, bm, (long)bx * 128, 768, 768);
}

// ---------------------------------------------------------------------------
// Fused attention: 1-D grid of 1536 blocks (= 8 * 192), XCD-swizzled so the
// 4 q-blocks sharing one (head,batch) K/V land on the same XCD's L2.
// LDS: Ks[256][64] swz | Vt[64][256] swz; Ps[64][256] swz aliases Ks.
// S computed transposed (mfma(bk,aq)): lane holds q=wave*16+lrow fixed,
// keys nt*16+quad*4+{0..3} -> softmax needs only shfl_xor 16,32.
// Pre-PV barrier is lgkmcnt-only: the attn-prob f32 stores (64 KB/block,
// 100 MB total) stay in flight and overlap the PV MFMAs.
// ---------------------------------------------------------------------------
__global__ __launch_bounds__(256, 2)
void attn_kernel(const _Float16* __restrict__ Qg, const _Float16* __restrict__ KVg,
                 float* __restrict__ attn_out, _Float16* __restrict__ Og) {
    __shared__ _Float16 sh[32768];          // 64 KB
    _Float16* Ks = sh;
    _Float16* Vt = sh + 16384;
    _Float16* Ps = sh;                      // aliases Ks after S phase

    const int tid  = threadIdx.x;
    const int wave = tid >> 6, lane = tid & 63;
    const int lrow = lane & 15, quad = lane >> 4;
    const int f = blockIdx.x;
    const int w = ((f & 7) * 192) + (f >> 3);        // 1536 = 8*192, bijective
    const int qb = w & 3;
    const int hb = w >> 2;
    const int h = hb % 12, b = hb / 12;
    const long qrow0 = (long)b * 256 + qb * 64;
    const long krow0 = (long)b * 256;

    // Q fragments from global (A layout: idx=lane&15 -> q, k=quad*8+j)
    f16x8 aq[2];
#pragma unroll
    for (int ks = 0; ks < 2; ++ks)
        aq[ks] = *(const f16x8*)(Qg + (qrow0 + wave * 16 + lrow) * 768 + h * 64 + ks * 32 + quad * 8);

    // K -> LDS async, swizzled
#pragma unroll
    for (int it = 0; it < 8; ++it) {
        int seg = tid + it * 256;
        int rr = seg >> 3, pp = seg & 7;
        int cc = ((pp ^ (rr & 7)) << 3);
        gload_lds16(KVg + (krow0 + rr) * 1536 + h * 64 + cc, Ks + seg * 8);
    }
    // V -> LDS transposed (V^T[d][key]), swizzled 16B blocks
#pragma unroll
    for (int it = 0; it < 8; ++it) {
        int seg = tid + it * 256;
        int key = seg >> 3, d0 = (seg & 7) * 8;
        f16x8 v = *(const f16x8*)(KVg + (krow0 + key) * 1536 + 768 + h * 64 + d0);
#pragma unroll
        for (int i = 0; i < 8; ++i) {
            int d = d0 + i;
            Vt[d * 256 + ((((key >> 3) ^ (d & 7)) << 3) | (key & 7))] = v[i];
        }
    }
    __syncthreads();

    // S^T = K Q^T : sacc[nt] lane holds keys nt*16+quad*4+{0..3}, q=wave*16+lrow
    f32x4 sacc[16];
    const f32x4 fz = {0.f, 0.f, 0.f, 0.f};
#pragma unroll
    for (int nt = 0; nt < 16; ++nt) sacc[nt] = fz;
#pragma unroll
    for (int ks = 0; ks < 2; ++ks) {
#pragma unroll
        for (int nt = 0; nt < 16; ++nt) {
            int r = nt * 16 + lrow;
            f16x8 bk = *(const f16x8*)(Ks + r * 64 + (((ks * 4 + quad) ^ (r & 7)) << 3));
            sacc[nt] = __builtin_amdgcn_mfma_f32_16x16x32_f16(bk, aq[ks], sacc[nt], 0, 0, 0);
        }
    }

    // softmax over keys for q=wave*16+lrow: 64 in-lane + quads (shfl 16,32).
    // scale (0.125) already folded into Wq.
    float m = -1e30f;
#pragma unroll
    for (int nt = 0; nt < 16; ++nt)
#pragma unroll
        for (int j = 0; j < 4; ++j) m = fmaxf(m, sacc[nt][j]);
    m = fmaxf(m, __shfl_xor(m, 16));
    m = fmaxf(m, __shfl_xor(m, 32));
    float s = 0.f;
#pragma unroll
    for (int nt = 0; nt < 16; ++nt)
#pragma unroll
        for (int j = 0; j < 4; ++j) {
            float p = __expf(sacc[nt][j] - m);
            sacc[nt][j] = p; s += p;
        }
    s += __shfl_xor(s, 16);
    s += __shfl_xor(s, 32);
    const float li = 1.f / s;

    __syncthreads();   // all waves done reading Ks before Ps overwrites it

    // write attn (float4, stays in flight through PV) + stage normalized P (LDS)
    const long abase = (((long)b * 12 + h) * 256 + qb * 64) * 256;
    const int q = wave * 16 + lrow;
#pragma unroll
    for (int nt = 0; nt < 16; ++nt) {
        float4 o = { sacc[nt][0] * li, sacc[nt][1] * li, sacc[nt][2] * li, sacc[nt][3] * li };
        *(float4*)(attn_out + abase + (long)q * 256 + nt * 16 + quad * 4) = o;
        f16x4 hp = { (_Float16)o.x, (_Float16)o.y, (_Float16)o.z, (_Float16)o.w };
        int blk = nt * 2 + (quad >> 1);
        *(f16x4*)(Ps + q * 256 + ((blk ^ (q & 7)) << 3) + ((quad & 1) << 2)) = hp;
    }
    // Ps ds_writes must land (lgkmcnt), but do NOT drain the global stores (vmcnt)
    asm volatile("s_waitcnt lgkmcnt(0)" ::: "memory");
    __builtin_amdgcn_sched_barrier(0);
    __builtin_amdgcn_s_barrier();

    // O = P V : mfma(bv, ap) -> lane holds d=nt*16+quad*4+{0..3}, q=wave*16+lrow
    f32x4 oacc[4];
#pragma unroll
    for (int nt = 0; nt < 4; ++nt) oacc[nt] = fz;
#pragma unroll
    for (int ks = 0; ks < 8; ++ks) {
        int pr = wave * 16 + lrow;
        f16x8 ap = *(const f16x8*)(Ps + pr * 256 + (((ks * 4 + quad) ^ (pr & 7)) << 3));
#pragma unroll
        for (int nt = 0; nt < 4; ++nt) {
            int d = nt * 16 + lrow;
            f16x8 bv = *(const f16x8*)(Vt + d * 256 + (((ks * 4 + quad) ^ (d & 7)) << 3));
            oacc[nt] = __builtin_amdgcn_mfma_f32_16x16x32_f16(bv, ap, oacc[nt], 0, 0, 0);
        }
    }
#pragma unroll
    for (int nt = 0; nt < 4; ++nt) {
        f16x4 ho = { (_Float16)oacc[nt][0], (_Float16)oacc[nt][1],
                     (_Float16)oacc[nt][2], (_Float16)oacc[nt][3] };
        *(f16x4*)(Og + (qrow0 + wave * 16 + lrow) * 768 + h * 64 + nt * 16 + quad * 4) = ho;
    }
}

// ---------------------------------------------------------------------------
extern "C" void kernel_launch(void* const* d_in, const int* in_sizes, int n_in,
                              void* d_out, int out_size, void* d_ws, size_t ws_size,
                              hipStream_t stream) {
    const float* xmm   = (const float*)d_in[0];  // [32,256,768]
    const float* xv    = (const float*)d_in[1];  // [32,196,768]
    const float* xa    = (const float*)d_in[2];  // [32, 60,768]
    const float* Wq    = (const float*)d_in[3];  // [768,768]
    const float* Wkv   = (const float*)d_in[4];  // [768,1536]
    const float* Wproj = (const float*)d_in[5];  // [768,768]
    const float* bproj = (const float*)d_in[6];  // [768]

    float* out  = (float*)d_out;            // [32,256,768]
    float* attn = out + 6291456;            // [32,12,256,256]

    char* ws = (char*)d_ws;
    _Float16* xmm16  = (_Float16*)(ws);                   // 12,582,912 B
    _Float16* xsrc16 = (_Float16*)(ws + 12582912);        // 12,582,912 B
    _Float16* WqT    = (_Float16*)(ws + 25165824);        //  1,179,648 B
    _Float16* WkvT   = (_Float16*)(ws + 26345472);        //  2,359,296 B
    _Float16* WprojT = (_Float16*)(ws + 28704768);        //  1,179,648 B
    _Float16* Q16    = (_Float16*)(ws + 29884416);        // 12,582,912 B
    _Float16* KV16   = (_Float16*)(ws + 42467328);        // 25,165,824 B
    _Float16* O16    = xmm16;   // xmm16 dead after QKV GEMM; reuse for O

    prep_all<<<12864, 256, 0, stream>>>(xmm, xv, xa, Wq, Wkv, Wproj,
                                        xmm16, xsrc16, WqT, WkvT, WprojT);

    gemm_qkv<<<1152, 256, 0, stream>>>(xmm16, xsrc16, WqT, WkvT, Q16, KV16);

    attn_kernel<<<1536, 256, 0, stream>>>(Q16, KV16, attn, O16);

    gemm_proj<<<384, 256, 0, stream>>>(O16, WprojT, out, bproj);
}

// Round 5
// 264.843 us; speedup vs baseline: 1.1456x; 1.0244x over previous
//
#include <hip/hip_runtime.h>

// ---------------------------------------------------------------------------
// CrossAttention_LocalAVTokens: bs=32, nmm=256, nv=196, na=60 (nv+na=256),
// DIM=768, HEADS=12, hd=64. Outputs: out [32,256,768] f32, attn [32,12,256,256] f32.
// fp16 MFMA 16x16x32, fp32 accumulate.
// Round 7: attn kernel restructured to 48 KB LDS (K/V streamed through one
// 16 KB buffer in 128-key halves; Ps gets its own 32 KB region) -> 3 blocks/CU
// instead of 2 (+50% TLP on a latency-bound kernel). V loads issued early and
// held in regs; attn-prob stores still never drained by a vmcnt. GEMMs, prep
// byte-identical to the round-4 kernel that measured 271.3 us.
// ---------------------------------------------------------------------------

typedef __attribute__((ext_vector_type(8))) _Float16 f16x8;
typedef __attribute__((ext_vector_type(4))) _Float16 f16x4;
typedef __attribute__((ext_vector_type(4))) float    f32x4;

#define AS1 __attribute__((address_space(1)))
#define AS3 __attribute__((address_space(3)))

__device__ __forceinline__ void gload_lds16(const void* g, void* l) {
    void* gnc = const_cast<void*>(g);
    __builtin_amdgcn_global_load_lds((AS1 void*)gnc, (AS3 void*)l, 16, 0, 0);
}

// ---------------------------------------------------------------------------
// prep_all: blocks [0,12288): activation cast/concat (float4 coalesced).
// blocks [12288,12864): weight transpose via 64x64 LDS tile — both the global
// read (rows of W) and the global write (rows of W^T) are coalesced.
// ---------------------------------------------------------------------------
__global__ __launch_bounds__(256) void prep_all(const float* __restrict__ xmm,
                                                const float* __restrict__ xv,
                                                const float* __restrict__ xa,
                                                const float* __restrict__ Wq,
                                                const float* __restrict__ Wkv,
                                                const float* __restrict__ Wproj,
                                                _Float16* __restrict__ xmm16,
                                                _Float16* __restrict__ xsrc16,
                                                _Float16* __restrict__ WqT,
                                                _Float16* __restrict__ WkvT,
                                                _Float16* __restrict__ WprojT) {
    __shared__ _Float16 wlds[64][72];       // [n_local][k_local], padded
    int bid = blockIdx.x;
    if (bid < 12288) {
        int id = bid * 256 + threadIdx.x;         // 2 * 1572864 float4s
        float4 v;
        _Float16* dst;
        int off;
        if (id < 1572864) {
            v = ((const float4*)xmm)[id];
            dst = xmm16; off = id;
        } else {
            int t = id - 1572864;
            int c4 = t % 192;
            int r  = (t / 192) & 255;
            int b  = t / 49152;
            if (r < 196) v = ((const float4*)xv)[((long)b * 196 + r) * 192 + c4];
            else         v = ((const float4*)xa)[((long)b * 60 + (r - 196)) * 192 + c4];
            dst = xsrc16; off = t;
        }
        f16x4 h = { (_Float16)v.x, (_Float16)v.y, (_Float16)v.z, (_Float16)v.w };
        ((f16x4*)dst)[off] = h;
        return;
    }
    // ---- weight transpose tiles: 144 (Wq) + 288 (Wkv) + 144 (Wproj) ----
    int t = bid - 12288;
    const float* src; _Float16* dst; int W; float scale; int tk, tn;
    if (t < 144)      { src = Wq;    dst = WqT;    W = 768;  scale = 0.125f; tk = t % 12;  tn = t / 12; }
    else if (t < 432) { int u = t - 144; src = Wkv;   dst = WkvT;   W = 1536; scale = 1.0f; tk = u % 12; tn = u / 12; }
    else              { int u = t - 432; src = Wproj; dst = WprojT; W = 768;  scale = 1.0f; tk = u % 12; tn = u / 12; }
    const int tk0 = tk * 64, tn0 = tn * 64;
    const int rloc = threadIdx.x >> 4, c0 = (threadIdx.x & 15) * 4;
#pragma unroll
    for (int i = 0; i < 4; ++i) {
        int k = tk0 + rloc + 16 * i;                 // coalesced read: row k, cols tn0+c0..+3
        float4 v = *(const float4*)(src + (long)k * W + tn0 + c0);
        wlds[c0 + 0][rloc + 16 * i] = (_Float16)(v.x * scale);
        wlds[c0 + 1][rloc + 16 * i] = (_Float16)(v.y * scale);
        wlds[c0 + 2][rloc + 16 * i] = (_Float16)(v.z * scale);
        wlds[c0 + 3][rloc + 16 * i] = (_Float16)(v.w * scale);
    }
    __syncthreads();
#pragma unroll
    for (int i = 0; i < 4; ++i) {
        int nloc = rloc + 16 * i;                    // coalesced write: row tn0+nloc of W^T
        f16x4 h = *(const f16x4*)(&wlds[nloc][c0]);
        *(f16x4*)(dst + (long)(tn0 + nloc) * 768 + tk0 + c0) = h;
    }
}

// ---------------------------------------------------------------------------
// Shared GEMM body: C[M,N] = A[M,K] @ Bt[N,K]^T, 128x128 tile, BK=64, 4 waves.
// Single-buffer (32 KB LDS -> 3+ blocks/CU; implicit wave-level overlap hides
// the stage latency — measured better than explicit dbuf at 64 KB).
// mfma(bf, af) => lane holds C[row][col0..col0+3] -> vector stores.
// ---------------------------------------------------------------------------
template <int OUT_F32>
__device__ __forceinline__ void gemm_body(const _Float16* __restrict__ A,
                                          const _Float16* __restrict__ Bt,
                                          void* __restrict__ C,
                                          const float* __restrict__ bias,
                                          long bm, long bn, int N, int K) {
    __shared__ _Float16 As[128 * 64];
    __shared__ _Float16 Bs[128 * 64];

    const int tid  = threadIdx.x;
    const int wave = tid >> 6, lane = tid & 63;
    const int lrow = lane & 15, quad = lane >> 4;
    const int wm = (wave >> 1) * 64, wn = (wave & 1) * 64;

    f32x4 acc[4][4];
    const f32x4 fz = {0.f, 0.f, 0.f, 0.f};
#pragma unroll
    for (int mt = 0; mt < 4; ++mt)
#pragma unroll
        for (int nt = 0; nt < 4; ++nt) acc[mt][nt] = fz;

    for (int k0 = 0; k0 < K; k0 += 64) {
#pragma unroll
        for (int it = 0; it < 4; ++it) {
            int seg = tid + it * 256;                 // 1024 segs of 8 halves
            int rr = seg >> 3, pp = seg & 7;
            int cc = ((pp ^ (rr & 7)) << 3);          // swizzled source column
            gload_lds16(A  + (bm + rr) * (long)K + k0 + cc, As + seg * 8);
            gload_lds16(Bt + (bn + rr) * (long)K + k0 + cc, Bs + seg * 8);
        }
        __syncthreads();
#pragma unroll
        for (int ks = 0; ks < 2; ++ks) {
            f16x8 af[4], bf[4];
#pragma unroll
            for (int mt = 0; mt < 4; ++mt) {
                int r = wm + mt * 16 + lrow;
                af[mt] = *(const f16x8*)(As + r * 64 + (((ks * 4 + quad) ^ (r & 7)) << 3));
            }
#pragma unroll
            for (int nt = 0; nt < 4; ++nt) {
                int r = wn + nt * 16 + lrow;
                bf[nt] = *(const f16x8*)(Bs + r * 64 + (((ks * 4 + quad) ^ (r & 7)) << 3));
            }
#pragma unroll
            for (int mt = 0; mt < 4; ++mt)
#pragma unroll
                for (int nt = 0; nt < 4; ++nt)
                    acc[mt][nt] = __builtin_amdgcn_mfma_f32_16x16x32_f16(
                        bf[nt], af[mt], acc[mt][nt], 0, 0, 0);   // swapped: C^T tile
        }
        __syncthreads();
    }

    // epilogue: lane owns C[bm+wm+mt*16+lrow][bn+wn+nt*16+quad*4 + 0..3]
#pragma unroll
    for (int mt = 0; mt < 4; ++mt) {
        long row = bm + wm + mt * 16 + lrow;
#pragma unroll
        for (int nt = 0; nt < 4; ++nt) {
            long col0 = bn + wn + nt * 16 + quad * 4;
            if (OUT_F32) {
                float4 b4 = *(const float4*)(bias + col0);
                float4 o = { acc[mt][nt][0] + b4.x, acc[mt][nt][1] + b4.y,
                             acc[mt][nt][2] + b4.z, acc[mt][nt][3] + b4.w };
                *(float4*)((float*)C + row * N + col0) = o;
            } else {
                f16x4 h = { (_Float16)acc[mt][nt][0], (_Float16)acc[mt][nt][1],
                            (_Float16)acc[mt][nt][2], (_Float16)acc[mt][nt][3] };
                *(f16x4*)((_Float16*)C + row * N + col0) = h;
            }
        }
    }
}

// Merged Q + KV projection, 1-D grid of 1152 blocks (= 8 XCDs * 144).
// Bijective XCD swizzle: each XCD gets 144 consecutive work items = 8 full
// M-panels — A-panels read once into that XCD's L2, weights L2-resident.
__global__ __launch_bounds__(256, 2)
void gemm_qkv(const _Float16* __restrict__ xmm16, const _Float16* __restrict__ xsrc16,
              const _Float16* __restrict__ WqT, const _Float16* __restrict__ WkvT,
              _Float16* __restrict__ Q16, _Float16* __restrict__ KV16) {
    const int f = blockIdx.x;
    const int w = ((f & 7) * 144) + (f >> 3);        // 1152 = 8*144, bijective
    const int bx = w % 18;
    const long bm = (long)(w / 18) * 128;
    if (bx < 6) gemm_body<0>(xmm16,  WqT,  (void*)Q16,  nullptr, bm, (long)bx * 128,       768,  768);
    else        gemm_body<0>(xsrc16, WkvT, (void*)KV16, nullptr, bm, (long)(bx - 6) * 128, 1536, 768);
}

// Output projection (+bias), f32 out. 1-D grid of 384 blocks (= 8 * 48).
__global__ __launch_bounds__(256, 2)
void gemm_proj(const _Float16* __restrict__ O16, const _Float16* __restrict__ WprojT,
               float* __restrict__ out, const float* __restrict__ bias) {
    const int f = blockIdx.x;
    const int w = ((f & 7) * 48) + (f >> 3);         // 384 = 8*48, bijective
    const int bx = w % 6;
    const long bm = (long)(w / 6) * 128;
    gemm_body<1>(O16, WprojT, (void*)out, bias, bm, (long)bx * 128, 768, 768);
}

// ---------------------------------------------------------------------------
// Fused attention, 48 KB LDS (3 blocks/CU): K and V stream through one 16 KB
// buffer (KVbuf) in 128-key halves; Ps [64][256] f16 has its own 32 KB region.
// Grid 1536 (= 8 * 192) XCD-swizzled. S computed transposed (mfma(bk,aq)):
// lane holds q=wave*16+lrow fixed, keys nt*16+quad*4+{0..3}.
// Phase chain (7 raw barriers): K0 | QK^T(0..7) | K1+issue V0/V1 loads |
// QK^T(8..15) | softmax | attn-store + Ps + V0-scatter | PV(ks0..3) |
// V1-scatter | PV(ks4..7). All post-store barriers are lgkm-only so the
// 100 MB attn-prob store overlaps PV (V1-scatter's implicit waitcnt only
// needs the older V1 loads, which the younger stores satisfy at vmcnt(16)).
// Per-accumulator FLOP order identical to the 64 KB version -> bitwise-same
// output.
// ---------------------------------------------------------------------------
__global__ __launch_bounds__(256, 3)
void attn_kernel(const _Float16* __restrict__ Qg, const _Float16* __restrict__ KVg,
                 float* __restrict__ attn_out, _Float16* __restrict__ Og) {
    __shared__ _Float16 sh[24576];          // 48 KB
    _Float16* KVbuf = sh;                   // 8192 halves: K-half / V^T-half stream
    _Float16* Ps    = sh + 8192;            // 16384 halves: P [64][256] swizzled

    const int tid  = threadIdx.x;
    const int wave = tid >> 6, lane = tid & 63;
    const int lrow = lane & 15, quad = lane >> 4;
    const int f = blockIdx.x;
    const int w = ((f & 7) * 192) + (f >> 3);        // 1536 = 8*192, bijective
    const int qb = w & 3;
    const int hb = w >> 2;
    const int h = hb % 12, b = hb / 12;
    const long qrow0 = (long)b * 256 + qb * 64;
    const long krow0 = (long)b * 256;

    // Q fragments from global (A layout: idx=lane&15 -> q, k=quad*8+j)
    f16x8 aq[2];
#pragma unroll
    for (int ks = 0; ks < 2; ++ks)
        aq[ks] = *(const f16x8*)(Qg + (qrow0 + wave * 16 + lrow) * 768 + h * 64 + ks * 32 + quad * 8);

    // ---- K keys 0..127 -> KVbuf (async, swizzled) ----
#pragma unroll
    for (int it = 0; it < 4; ++it) {
        int seg = tid + it * 256;                    // 1024 segs (128 rows x 8)
        int rr = seg >> 3, pp = seg & 7;
        int cc = ((pp ^ (rr & 7)) << 3);
        gload_lds16(KVg + (krow0 + rr) * 1536 + h * 64 + cc, KVbuf + seg * 8);
    }
    asm volatile("s_waitcnt vmcnt(0)" ::: "memory");
    __builtin_amdgcn_s_barrier();                    // S1: K0 ready

    // ---- S^T half 0: keys 0..127 -> sacc[0..7] ----
    f32x4 sacc[16];
    const f32x4 fz = {0.f, 0.f, 0.f, 0.f};
#pragma unroll
    for (int nt = 0; nt < 16; ++nt) sacc[nt] = fz;
#pragma unroll
    for (int ks = 0; ks < 2; ++ks) {
#pragma unroll
        for (int nt = 0; nt < 8; ++nt) {
            int r = nt * 16 + lrow;                  // 0..127 (local == global)
            f16x8 bk = *(const f16x8*)(KVbuf + r * 64 + (((ks * 4 + quad) ^ (r & 7)) << 3));
            sacc[nt] = __builtin_amdgcn_mfma_f32_16x16x32_f16(bk, aq[ks], sacc[nt], 0, 0, 0);
        }
    }
    __builtin_amdgcn_s_barrier();                    // S2: K0 consumed

    // ---- K keys 128..255 -> KVbuf; issue BOTH V-half register loads ----
#pragma unroll
    for (int it = 0; it < 4; ++it) {
        int seg = tid + it * 256;
        int rr = seg >> 3, pp = seg & 7;
        int cc = ((pp ^ (rr & 7)) << 3);             // (rr+128)&7 == rr&7
        gload_lds16(KVg + (krow0 + 128 + rr) * 1536 + h * 64 + cc, KVbuf + seg * 8);
    }
    f16x8 v0r[4], v1r[4];
#pragma unroll
    for (int it = 0; it < 4; ++it) {
        int seg = tid + it * 256;                    // key_l = seg>>3, d0 = (seg&7)*8
        int key_l = seg >> 3, d0 = (seg & 7) * 8;
        v0r[it] = *(const f16x8*)(KVg + (krow0 + key_l) * 1536 + 768 + h * 64 + d0);
        v1r[it] = *(const f16x8*)(KVg + (krow0 + 128 + key_l) * 1536 + 768 + h * 64 + d0);
    }
    asm volatile("s_waitcnt vmcnt(0)" ::: "memory"); // K1 (and V regs) landed
    __builtin_amdgcn_s_barrier();                    // S3: K1 ready

    // ---- S^T half 1: keys 128..255 -> sacc[8..15] ----
#pragma unroll
    for (int ks = 0; ks < 2; ++ks) {
#pragma unroll
        for (int nt = 8; nt < 16; ++nt) {
            int r = nt * 16 + lrow;                  // 128..255
            int rl = r - 128;                        // rl&7 == r&7
            f16x8 bk = *(const f16x8*)(KVbuf + rl * 64 + (((ks * 4 + quad) ^ (rl & 7)) << 3));
            sacc[nt] = __builtin_amdgcn_mfma_f32_16x16x32_f16(bk, aq[ks], sacc[nt], 0, 0, 0);
        }
    }
    __builtin_amdgcn_s_barrier();                    // S4: K1 consumed, KVbuf free

    // ---- softmax over keys (regs only; scale folded into Wq) ----
    float m = -1e30f;
#pragma unroll
    for (int nt = 0; nt < 16; ++nt)
#pragma unroll
        for (int j = 0; j < 4; ++j) m = fmaxf(m, sacc[nt][j]);
    m = fmaxf(m, __shfl_xor(m, 16));
    m = fmaxf(m, __shfl_xor(m, 32));
    float s = 0.f;
#pragma unroll
    for (int nt = 0; nt < 16; ++nt)
#pragma unroll
        for (int j = 0; j < 4; ++j) {
            float p = __expf(sacc[nt][j] - m);
            sacc[nt][j] = p; s += p;
        }
    s += __shfl_xor(s, 16);
    s += __shfl_xor(s, 32);
    const float li = 1.f / s;

    // ---- V-half0 scatter into KVbuf as V^T[64][128] (swizzled 16B chunks) ----
#pragma unroll
    for (int it = 0; it < 4; ++it) {
        int seg = tid + it * 256;
        int key_l = seg >> 3, d0 = (seg & 7) * 8;
#pragma unroll
        for (int i = 0; i < 8; ++i) {
            int d = d0 + i;
            KVbuf[d * 128 + (((key_l >> 3) ^ (d & 7)) << 3) + (key_l & 7)] = v0r[it][i];
        }
    }

    // ---- write attn (float4, stays in flight) + stage normalized P ----
    const long abase = (((long)b * 12 + h) * 256 + qb * 64) * 256;
    const int q = wave * 16 + lrow;
#pragma unroll
    for (int nt = 0; nt < 16; ++nt) {
        float4 o = { sacc[nt][0] * li, sacc[nt][1] * li, sacc[nt][2] * li, sacc[nt][3] * li };
        *(float4*)(attn_out + abase + (long)q * 256 + nt * 16 + quad * 4) = o;
        f16x4 hp = { (_Float16)o.x, (_Float16)o.y, (_Float16)o.z, (_Float16)o.w };
        int blk = nt * 2 + (quad >> 1);
        *(f16x4*)(Ps + q * 256 + ((blk ^ (q & 7)) << 3) + ((quad & 1) << 2)) = hp;
    }
    // Ps + V0 ds_writes must land; do NOT drain the global stores (vmcnt)
    asm volatile("s_waitcnt lgkmcnt(0)" ::: "memory");
    __builtin_amdgcn_sched_barrier(0);
    __builtin_amdgcn_s_barrier();                    // S5: P + V^T-half0 ready

    // ---- O = P V, keys 0..127 (ks 0..3) ----
    f32x4 oacc[4];
#pragma unroll
    for (int nt = 0; nt < 4; ++nt) oacc[nt] = fz;
    const int pr = wave * 16 + lrow;
#pragma unroll
    for (int ks = 0; ks < 4; ++ks) {
        f16x8 ap = *(const f16x8*)(Ps + pr * 256 + (((ks * 4 + quad) ^ (pr & 7)) << 3));
#pragma unroll
        for (int nt = 0; nt < 4; ++nt) {
            int d = nt * 16 + lrow;
            f16x8 bv = *(const f16x8*)(KVbuf + d * 128 + ((((ks & 3) * 4 + quad) ^ (d & 7)) << 3));
            oacc[nt] = __builtin_amdgcn_mfma_f32_16x16x32_f16(bv, ap, oacc[nt], 0, 0, 0);
        }
    }
    __builtin_amdgcn_s_barrier();                    // S6: V^T-half0 consumed

    // ---- V-half1 scatter (implicit waitcnt needs only the older V1 loads) ----
#pragma unroll
    for (int it = 0; it < 4; ++it) {
        int seg = tid + it * 256;
        int key_l = seg >> 3, d0 = (seg & 7) * 8;
#pragma unroll
        for (int i = 0; i < 8; ++i) {
            int d = d0 + i;
            KVbuf[d * 128 + (((key_l >> 3) ^ (d & 7)) << 3) + (key_l & 7)] = v1r[it][i];
        }
    }
    asm volatile("s_waitcnt lgkmcnt(0)" ::: "memory");
    __builtin_amdgcn_sched_barrier(0);
    __builtin_amdgcn_s_barrier();                    // S7: V^T-half1 ready

    // ---- O = P V, keys 128..255 (ks 4..7) ----
#pragma unroll
    for (int ks = 4; ks < 8; ++ks) {
        f16x8 ap = *(const f16x8*)(Ps + pr * 256 + (((ks * 4 + quad) ^ (pr & 7)) << 3));
#pragma unroll
        for (int nt = 0; nt < 4; ++nt) {
            int d = nt * 16 + lrow;
            f16x8 bv = *(const f16x8*)(KVbuf + d * 128 + ((((ks & 3) * 4 + quad) ^ (d & 7)) << 3));
            oacc[nt] = __builtin_amdgcn_mfma_f32_16x16x32_f16(bv, ap, oacc[nt], 0, 0, 0);
        }
    }
#pragma unroll
    for (int nt = 0; nt < 4; ++nt) {
        f16x4 ho = { (_Float16)oacc[nt][0], (_Float16)oacc[nt][1],
                     (_Float16)oacc[nt][2], (_Float16)oacc[nt][3] };
        *(f16x4*)(Og + (qrow0 + wave * 16 + lrow) * 768 + h * 64 + nt * 16 + quad * 4) = ho;
    }
}

// ---------------------------------------------------------------------------
extern "C" void kernel_launch(void* const* d_in, const int* in_sizes, int n_in,
                              void* d_out, int out_size, void* d_ws, size_t ws_size,
                              hipStream_t stream) {
    const float* xmm   = (const float*)d_in[0];  // [32,256,768]
    const float* xv    = (const float*)d_in[1];  // [32,196,768]
    const float* xa    = (const float*)d_in[2];  // [32, 60,768]
    const float* Wq    = (const float*)d_in[3];  // [768,768]
    const float* Wkv   = (const float*)d_in[4];  // [768,1536]
    const float* Wproj = (const float*)d_in[5];  // [768,768]
    const float* bproj = (const float*)d_in[6];  // [768]

    float* out  = (float*)d_out;            // [32,256,768]
    float* attn = out + 6291456;            // [32,12,256,256]

    char* ws = (char*)d_ws;
    _Float16* xmm16  = (_Float16*)(ws);                   // 12,582,912 B
    _Float16* xsrc16 = (_Float16*)(ws + 12582912);        // 12,582,912 B
    _Float16* WqT    = (_Float16*)(ws + 25165824);        //  1,179,648 B
    _Float16* WkvT   = (_Float16*)(ws + 26345472);        //  2,359,296 B
    _Float16* WprojT = (_Float16*)(ws + 28704768);        //  1,179,648 B
    _Float16* Q16    = (_Float16*)(ws + 29884416);        // 12,582,912 B
    _Float16* KV16   = (_Float16*)(ws + 42467328);        // 25,165,824 B
    _Float16* O16    = xmm16;   // xmm16 dead after QKV GEMM; reuse for O

    prep_all<<<12864, 256, 0, stream>>>(xmm, xv, xa, Wq, Wkv, Wproj,
                                        xmm16, xsrc16, WqT, WkvT, WprojT);

    gemm_qkv<<<1152, 256, 0, stream>>>(xmm16, xsrc16, WqT, WkvT, Q16, KV16);

    attn_kernel<<<1536, 256, 0, stream>>>(Q16, KV16, attn, O16);

    gemm_proj<<<384, 256, 0, stream>>>(O16, WprojT, out, bproj);
}

// Round 6
// 262.743 us; speedup vs baseline: 1.1548x; 1.0080x over previous
//
#include <hip/hip_runtime.h>

// ---------------------------------------------------------------------------
// CrossAttention_LocalAVTokens: bs=32, nmm=256, nv=196, na=60 (nv+na=256),
// DIM=768, HEADS=12, hd=64. Outputs: out [32,256,768] f32, attn [32,12,256,256] f32.
// fp16 MFMA 16x16x32, fp32 accumulate.
// Round 8: (1) gemm kernels -> __launch_bounds__(256,3): cap VGPR ~170 so
// occupancy is 3 blocks/CU (LDS 32KB allows 5; bound 2 allowed 256 VGPR and
// possibly capped us at 2); gemm_qkv collapsed to one gemm_body call with
// selected operands (half the code, less regalloc pressure). (2) attn S3
// waits vmcnt(8) — only the 8 K1 gload_lds, leaving the 8 V register loads
// in flight until softmax (issue order pinned by sched_barrier). Rest
// byte-identical to the 264.8 us round-5 kernel.
// ---------------------------------------------------------------------------

typedef __attribute__((ext_vector_type(8))) _Float16 f16x8;
typedef __attribute__((ext_vector_type(4))) _Float16 f16x4;
typedef __attribute__((ext_vector_type(4))) float    f32x4;

#define AS1 __attribute__((address_space(1)))
#define AS3 __attribute__((address_space(3)))

__device__ __forceinline__ void gload_lds16(const void* g, void* l) {
    void* gnc = const_cast<void*>(g);
    __builtin_amdgcn_global_load_lds((AS1 void*)gnc, (AS3 void*)l, 16, 0, 0);
}

// ---------------------------------------------------------------------------
// prep_all: blocks [0,12288): activation cast/concat (float4 coalesced).
// blocks [12288,12864): weight transpose via 64x64 LDS tile — both the global
// read (rows of W) and the global write (rows of W^T) are coalesced.
// ---------------------------------------------------------------------------
__global__ __launch_bounds__(256) void prep_all(const float* __restrict__ xmm,
                                                const float* __restrict__ xv,
                                                const float* __restrict__ xa,
                                                const float* __restrict__ Wq,
                                                const float* __restrict__ Wkv,
                                                const float* __restrict__ Wproj,
                                                _Float16* __restrict__ xmm16,
                                                _Float16* __restrict__ xsrc16,
                                                _Float16* __restrict__ WqT,
                                                _Float16* __restrict__ WkvT,
                                                _Float16* __restrict__ WprojT) {
    __shared__ _Float16 wlds[64][72];       // [n_local][k_local], padded
    int bid = blockIdx.x;
    if (bid < 12288) {
        int id = bid * 256 + threadIdx.x;         // 2 * 1572864 float4s
        float4 v;
        _Float16* dst;
        int off;
        if (id < 1572864) {
            v = ((const float4*)xmm)[id];
            dst = xmm16; off = id;
        } else {
            int t = id - 1572864;
            int c4 = t % 192;
            int r  = (t / 192) & 255;
            int b  = t / 49152;
            if (r < 196) v = ((const float4*)xv)[((long)b * 196 + r) * 192 + c4];
            else         v = ((const float4*)xa)[((long)b * 60 + (r - 196)) * 192 + c4];
            dst = xsrc16; off = t;
        }
        f16x4 h = { (_Float16)v.x, (_Float16)v.y, (_Float16)v.z, (_Float16)v.w };
        ((f16x4*)dst)[off] = h;
        return;
    }
    // ---- weight transpose tiles: 144 (Wq) + 288 (Wkv) + 144 (Wproj) ----
    int t = bid - 12288;
    const float* src; _Float16* dst; int W; float scale; int tk, tn;
    if (t < 144)      { src = Wq;    dst = WqT;    W = 768;  scale = 0.125f; tk = t % 12;  tn = t / 12; }
    else if (t < 432) { int u = t - 144; src = Wkv;   dst = WkvT;   W = 1536; scale = 1.0f; tk = u % 12; tn = u / 12; }
    else              { int u = t - 432; src = Wproj; dst = WprojT; W = 768;  scale = 1.0f; tk = u % 12; tn = u / 12; }
    const int tk0 = tk * 64, tn0 = tn * 64;
    const int rloc = threadIdx.x >> 4, c0 = (threadIdx.x & 15) * 4;
#pragma unroll
    for (int i = 0; i < 4; ++i) {
        int k = tk0 + rloc + 16 * i;                 // coalesced read: row k, cols tn0+c0..+3
        float4 v = *(const float4*)(src + (long)k * W + tn0 + c0);
        wlds[c0 + 0][rloc + 16 * i] = (_Float16)(v.x * scale);
        wlds[c0 + 1][rloc + 16 * i] = (_Float16)(v.y * scale);
        wlds[c0 + 2][rloc + 16 * i] = (_Float16)(v.z * scale);
        wlds[c0 + 3][rloc + 16 * i] = (_Float16)(v.w * scale);
    }
    __syncthreads();
#pragma unroll
    for (int i = 0; i < 4; ++i) {
        int nloc = rloc + 16 * i;                    // coalesced write: row tn0+nloc of W^T
        f16x4 h = *(const f16x4*)(&wlds[nloc][c0]);
        *(f16x4*)(dst + (long)(tn0 + nloc) * 768 + tk0 + c0) = h;
    }
}

// ---------------------------------------------------------------------------
// Shared GEMM body: C[M,N] = A[M,K] @ Bt[N,K]^T, 128x128 tile, BK=64, 4 waves.
// Single-buffer (32 KB LDS; at launch_bounds(256,3) -> 3 blocks/CU; implicit
// wave-level overlap hides the stage latency).
// mfma(bf, af) => lane holds C[row][col0..col0+3] -> vector stores.
// ---------------------------------------------------------------------------
template <int OUT_F32>
__device__ __forceinline__ void gemm_body(const _Float16* __restrict__ A,
                                          const _Float16* __restrict__ Bt,
                                          void* __restrict__ C,
                                          const float* __restrict__ bias,
                                          long bm, long bn, int N, int K) {
    __shared__ _Float16 As[128 * 64];
    __shared__ _Float16 Bs[128 * 64];

    const int tid  = threadIdx.x;
    const int wave = tid >> 6, lane = tid & 63;
    const int lrow = lane & 15, quad = lane >> 4;
    const int wm = (wave >> 1) * 64, wn = (wave & 1) * 64;

    f32x4 acc[4][4];
    const f32x4 fz = {0.f, 0.f, 0.f, 0.f};
#pragma unroll
    for (int mt = 0; mt < 4; ++mt)
#pragma unroll
        for (int nt = 0; nt < 4; ++nt) acc[mt][nt] = fz;

    for (int k0 = 0; k0 < K; k0 += 64) {
#pragma unroll
        for (int it = 0; it < 4; ++it) {
            int seg = tid + it * 256;                 // 1024 segs of 8 halves
            int rr = seg >> 3, pp = seg & 7;
            int cc = ((pp ^ (rr & 7)) << 3);          // swizzled source column
            gload_lds16(A  + (bm + rr) * (long)K + k0 + cc, As + seg * 8);
            gload_lds16(Bt + (bn + rr) * (long)K + k0 + cc, Bs + seg * 8);
        }
        __syncthreads();
#pragma unroll
        for (int ks = 0; ks < 2; ++ks) {
            f16x8 af[4], bf[4];
#pragma unroll
            for (int mt = 0; mt < 4; ++mt) {
                int r = wm + mt * 16 + lrow;
                af[mt] = *(const f16x8*)(As + r * 64 + (((ks * 4 + quad) ^ (r & 7)) << 3));
            }
#pragma unroll
            for (int nt = 0; nt < 4; ++nt) {
                int r = wn + nt * 16 + lrow;
                bf[nt] = *(const f16x8*)(Bs + r * 64 + (((ks * 4 + quad) ^ (r & 7)) << 3));
            }
#pragma unroll
            for (int mt = 0; mt < 4; ++mt)
#pragma unroll
                for (int nt = 0; nt < 4; ++nt)
                    acc[mt][nt] = __builtin_amdgcn_mfma_f32_16x16x32_f16(
                        bf[nt], af[mt], acc[mt][nt], 0, 0, 0);   // swapped: C^T tile
        }
        __syncthreads();
    }

    // epilogue: lane owns C[bm+wm+mt*16+lrow][bn+wn+nt*16+quad*4 + 0..3]
#pragma unroll
    for (int mt = 0; mt < 4; ++mt) {
        long row = bm + wm + mt * 16 + lrow;
#pragma unroll
        for (int nt = 0; nt < 4; ++nt) {
            long col0 = bn + wn + nt * 16 + quad * 4;
            if (OUT_F32) {
                float4 b4 = *(const float4*)(bias + col0);
                float4 o = { acc[mt][nt][0] + b4.x, acc[mt][nt][1] + b4.y,
                             acc[mt][nt][2] + b4.z, acc[mt][nt][3] + b4.w };
                *(float4*)((float*)C + row * N + col0) = o;
            } else {
                f16x4 h = { (_Float16)acc[mt][nt][0], (_Float16)acc[mt][nt][1],
                            (_Float16)acc[mt][nt][2], (_Float16)acc[mt][nt][3] };
                *(f16x4*)((_Float16*)C + row * N + col0) = h;
            }
        }
    }
}

// Merged Q + KV projection, 1-D grid of 1152 blocks (= 8 XCDs * 144).
// Bijective XCD swizzle; single gemm_body call with selected operands.
__global__ __launch_bounds__(256, 3)
void gemm_qkv(const _Float16* __restrict__ xmm16, const _Float16* __restrict__ xsrc16,
              const _Float16* __restrict__ WqT, const _Float16* __restrict__ WkvT,
              _Float16* __restrict__ Q16, _Float16* __restrict__ KV16) {
    const int f = blockIdx.x;
    const int w = ((f & 7) * 144) + (f >> 3);        // 1152 = 8*144, bijective
    const int bx = w % 18;
    const long bm = (long)(w / 18) * 128;
    const bool isq = (bx < 6);
    const _Float16* A  = isq ? xmm16 : xsrc16;
    const _Float16* Bt = isq ? WqT   : WkvT;
    _Float16*       Cp = isq ? Q16   : KV16;
    const long bn = isq ? (long)bx * 128 : (long)(bx - 6) * 128;
    const int  N  = isq ? 768 : 1536;
    gemm_body<0>(A, Bt, (void*)Cp, nullptr, bm, bn, N, 768);
}

// Output projection (+bias), f32 out. 1-D grid of 384 blocks (= 8 * 48).
__global__ __launch_bounds__(256, 3)
void gemm_proj(const _Float16* __restrict__ O16, const _Float16* __restrict__ WprojT,
               float* __restrict__ out, const float* __restrict__ bias) {
    const int f = blockIdx.x;
    const int w = ((f & 7) * 48) + (f >> 3);         // 384 = 8*48, bijective
    const int bx = w % 6;
    const long bm = (long)(w / 6) * 128;
    gemm_body<1>(O16, WprojT, (void*)out, bias, bm, (long)bx * 128, 768, 768);
}

// ---------------------------------------------------------------------------
// Fused attention, 48 KB LDS (3 blocks/CU): K and V stream through one 16 KB
// buffer (KVbuf) in 128-key halves; Ps [64][256] f16 has its own 32 KB region.
// Grid 1536 (= 8 * 192) XCD-swizzled. S computed transposed (mfma(bk,aq)):
// lane holds q=wave*16+lrow fixed, keys nt*16+quad*4+{0..3}.
// S3 waits vmcnt(8): only the 8 K1 gload_lds (older), leaving the 8 V
// register loads (younger, pinned by sched_barrier) in flight until the
// V0-scatter after softmax. All post-store barriers lgkm-only so the 100 MB
// attn-prob store overlaps PV.
// ---------------------------------------------------------------------------
__global__ __launch_bounds__(256, 3)
void attn_kernel(const _Float16* __restrict__ Qg, const _Float16* __restrict__ KVg,
                 float* __restrict__ attn_out, _Float16* __restrict__ Og) {
    __shared__ _Float16 sh[24576];          // 48 KB
    _Float16* KVbuf = sh;                   // 8192 halves: K-half / V^T-half stream
    _Float16* Ps    = sh + 8192;            // 16384 halves: P [64][256] swizzled

    const int tid  = threadIdx.x;
    const int wave = tid >> 6, lane = tid & 63;
    const int lrow = lane & 15, quad = lane >> 4;
    const int f = blockIdx.x;
    const int w = ((f & 7) * 192) + (f >> 3);        // 1536 = 8*192, bijective
    const int qb = w & 3;
    const int hb = w >> 2;
    const int h = hb % 12, b = hb / 12;
    const long qrow0 = (long)b * 256 + qb * 64;
    const long krow0 = (long)b * 256;

    // Q fragments from global (A layout: idx=lane&15 -> q, k=quad*8+j)
    f16x8 aq[2];
#pragma unroll
    for (int ks = 0; ks < 2; ++ks)
        aq[ks] = *(const f16x8*)(Qg + (qrow0 + wave * 16 + lrow) * 768 + h * 64 + ks * 32 + quad * 8);

    // ---- K keys 0..127 -> KVbuf (async, swizzled) ----
#pragma unroll
    for (int it = 0; it < 4; ++it) {
        int seg = tid + it * 256;                    // 1024 segs (128 rows x 8)
        int rr = seg >> 3, pp = seg & 7;
        int cc = ((pp ^ (rr & 7)) << 3);
        gload_lds16(KVg + (krow0 + rr) * 1536 + h * 64 + cc, KVbuf + seg * 8);
    }
    asm volatile("s_waitcnt vmcnt(0)" ::: "memory");
    __builtin_amdgcn_s_barrier();                    // S1: K0 ready

    // ---- S^T half 0: keys 0..127 -> sacc[0..7] ----
    f32x4 sacc[16];
    const f32x4 fz = {0.f, 0.f, 0.f, 0.f};
#pragma unroll
    for (int nt = 0; nt < 16; ++nt) sacc[nt] = fz;
#pragma unroll
    for (int ks = 0; ks < 2; ++ks) {
#pragma unroll
        for (int nt = 0; nt < 8; ++nt) {
            int r = nt * 16 + lrow;                  // 0..127 (local == global)
            f16x8 bk = *(const f16x8*)(KVbuf + r * 64 + (((ks * 4 + quad) ^ (r & 7)) << 3));
            sacc[nt] = __builtin_amdgcn_mfma_f32_16x16x32_f16(bk, aq[ks], sacc[nt], 0, 0, 0);
        }
    }
    __builtin_amdgcn_s_barrier();                    // S2: K0 consumed

    // ---- K keys 128..255 -> KVbuf (8 gload_lds, issued FIRST) ----
#pragma unroll
    for (int it = 0; it < 4; ++it) {
        int seg = tid + it * 256;
        int rr = seg >> 3, pp = seg & 7;
        int cc = ((pp ^ (rr & 7)) << 3);             // (rr+128)&7 == rr&7
        gload_lds16(KVg + (krow0 + 128 + rr) * 1536 + h * 64 + cc, KVbuf + seg * 8);
    }
    __builtin_amdgcn_sched_barrier(0);               // pin: K1 older than V loads
    // ---- both V-half register loads (8 younger VMEM ops, stay in flight) ----
    f16x8 v0r[4], v1r[4];
#pragma unroll
    for (int it = 0; it < 4; ++it) {
        int seg = tid + it * 256;                    // key_l = seg>>3, d0 = (seg&7)*8
        int key_l = seg >> 3, d0 = (seg & 7) * 8;
        v0r[it] = *(const f16x8*)(KVg + (krow0 + key_l) * 1536 + 768 + h * 64 + d0);
        v1r[it] = *(const f16x8*)(KVg + (krow0 + 128 + key_l) * 1536 + 768 + h * 64 + d0);
    }
    __builtin_amdgcn_sched_barrier(0);
    asm volatile("s_waitcnt vmcnt(8)" ::: "memory"); // K1 landed; V still in flight
    __builtin_amdgcn_s_barrier();                    // S3: K1 ready

    // ---- S^T half 1: keys 128..255 -> sacc[8..15] ----
#pragma unroll
    for (int ks = 0; ks < 2; ++ks) {
#pragma unroll
        for (int nt = 8; nt < 16; ++nt) {
            int r = nt * 16 + lrow;                  // 128..255
            int rl = r - 128;                        // rl&7 == r&7
            f16x8 bk = *(const f16x8*)(KVbuf + rl * 64 + (((ks * 4 + quad) ^ (rl & 7)) << 3));
            sacc[nt] = __builtin_amdgcn_mfma_f32_16x16x32_f16(bk, aq[ks], sacc[nt], 0, 0, 0);
        }
    }
    __builtin_amdgcn_s_barrier();                    // S4: K1 consumed, KVbuf free

    // ---- softmax over keys (regs only; scale folded into Wq) ----
    float m = -1e30f;
#pragma unroll
    for (int nt = 0; nt < 16; ++nt)
#pragma unroll
        for (int j = 0; j < 4; ++j) m = fmaxf(m, sacc[nt][j]);
    m = fmaxf(m, __shfl_xor(m, 16));
    m = fmaxf(m, __shfl_xor(m, 32));
    float s = 0.f;
#pragma unroll
    for (int nt = 0; nt < 16; ++nt)
#pragma unroll
        for (int j = 0; j < 4; ++j) {
            float p = __expf(sacc[nt][j] - m);
            sacc[nt][j] = p; s += p;
        }
    s += __shfl_xor(s, 16);
    s += __shfl_xor(s, 32);
    const float li = 1.f / s;

    // ---- V-half0 scatter into KVbuf as V^T[64][128] (swizzled 16B chunks) ----
#pragma unroll
    for (int it = 0; it < 4; ++it) {
        int seg = tid + it * 256;
        int key_l = seg >> 3, d0 = (seg & 7) * 8;
#pragma unroll
        for (int i = 0; i < 8; ++i) {
            int d = d0 + i;
            KVbuf[d * 128 + (((key_l >> 3) ^ (d & 7)) << 3) + (key_l & 7)] = v0r[it][i];
        }
    }

    // ---- write attn (float4, stays in flight) + stage normalized P ----
    const long abase = (((long)b * 12 + h) * 256 + qb * 64) * 256;
    const int q = wave * 16 + lrow;
#pragma unroll
    for (int nt = 0; nt < 16; ++nt) {
        float4 o = { sacc[nt][0] * li, sacc[nt][1] * li, sacc[nt][2] * li, sacc[nt][3] * li };
        *(float4*)(attn_out + abase + (long)q * 256 + nt * 16 + quad * 4) = o;
        f16x4 hp = { (_Float16)o.x, (_Float16)o.y, (_Float16)o.z, (_Float16)o.w };
        int blk = nt * 2 + (quad >> 1);
        *(f16x4*)(Ps + q * 256 + ((blk ^ (q & 7)) << 3) + ((quad & 1) << 2)) = hp;
    }
    // Ps + V0 ds_writes must land; do NOT drain the global stores (vmcnt)
    asm volatile("s_waitcnt lgkmcnt(0)" ::: "memory");
    __builtin_amdgcn_sched_barrier(0);
    __builtin_amdgcn_s_barrier();                    // S5: P + V^T-half0 ready

    // ---- O = P V, keys 0..127 (ks 0..3) ----
    f32x4 oacc[4];
#pragma unroll
    for (int nt = 0; nt < 4; ++nt) oacc[nt] = fz;
    const int pr = wave * 16 + lrow;
#pragma unroll
    for (int ks = 0; ks < 4; ++ks) {
        f16x8 ap = *(const f16x8*)(Ps + pr * 256 + (((ks * 4 + quad) ^ (pr & 7)) << 3));
#pragma unroll
        for (int nt = 0; nt < 4; ++nt) {
            int d = nt * 16 + lrow;
            f16x8 bv = *(const f16x8*)(KVbuf + d * 128 + ((((ks & 3) * 4 + quad) ^ (d & 7)) << 3));
            oacc[nt] = __builtin_amdgcn_mfma_f32_16x16x32_f16(bv, ap, oacc[nt], 0, 0, 0);
        }
    }
    __builtin_amdgcn_s_barrier();                    // S6: V^T-half0 consumed

    // ---- V-half1 scatter (implicit waitcnt needs only the older V1 loads) ----
#pragma unroll
    for (int it = 0; it < 4; ++it) {
        int seg = tid + it * 256;
        int key_l = seg >> 3, d0 = (seg & 7) * 8;
#pragma unroll
        for (int i = 0; i < 8; ++i) {
            int d = d0 + i;
            KVbuf[d * 128 + (((key_l >> 3) ^ (d & 7)) << 3) + (key_l & 7)] = v1r[it][i];
        }
    }
    asm volatile("s_waitcnt lgkmcnt(0)" ::: "memory");
    __builtin_amdgcn_sched_barrier(0);
    __builtin_amdgcn_s_barrier();                    // S7: V^T-half1 ready

    // ---- O = P V, keys 128..255 (ks 4..7) ----
#pragma unroll
    for (int ks = 4; ks < 8; ++ks) {
        f16x8 ap = *(const f16x8*)(Ps + pr * 256 + (((ks * 4 + quad) ^ (pr & 7)) << 3));
#pragma unroll
        for (int nt = 0; nt < 4; ++nt) {
            int d = nt * 16 + lrow;
            f16x8 bv = *(const f16x8*)(KVbuf + d * 128 + ((((ks & 3) * 4 + quad) ^ (d & 7)) << 3));
            oacc[nt] = __builtin_amdgcn_mfma_f32_16x16x32_f16(bv, ap, oacc[nt], 0, 0, 0);
        }
    }
#pragma unroll
    for (int nt = 0; nt < 4; ++nt) {
        f16x4 ho = { (_Float16)oacc[nt][0], (_Float16)oacc[nt][1],
                     (_Float16)oacc[nt][2], (_Float16)oacc[nt][3] };
        *(f16x4*)(Og + (qrow0 + wave * 16 + lrow) * 768 + h * 64 + nt * 16 + quad * 4) = ho;
    }
}

// ---------------------------------------------------------------------------
extern "C" void kernel_launch(void* const* d_in, const int* in_sizes, int n_in,
                              void* d_out, int out_size, void* d_ws, size_t ws_size,
                              hipStream_t stream) {
    const float* xmm   = (const float*)d_in[0];  // [32,256,768]
    const float* xv    = (const float*)d_in[1];  // [32,196,768]
    const float* xa    = (const float*)d_in[2];  // [32, 60,768]
    const float* Wq    = (const float*)d_in[3];  // [768,768]
    const float* Wkv   = (const float*)d_in[4];  // [768,1536]
    const float* Wproj = (const float*)d_in[5];  // [768,768]
    const float* bproj = (const float*)d_in[6];  // [768]

    float* out  = (float*)d_out;            // [32,256,768]
    float* attn = out + 6291456;            // [32,12,256,256]

    char* ws = (char*)d_ws;
    _Float16* xmm16  = (_Float16*)(ws);                   // 12,582,912 B
    _Float16* xsrc16 = (_Float16*)(ws + 12582912);        // 12,582,912 B
    _Float16* WqT    = (_Float16*)(ws + 25165824);        //  1,179,648 B
    _Float16* WkvT   = (_Float16*)(ws + 26345472);        //  2,359,296 B
    _Float16* WprojT = (_Float16*)(ws + 28704768);        //  1,179,648 B
    _Float16* Q16    = (_Float16*)(ws + 29884416);        // 12,582,912 B
    _Float16* KV16   = (_Float16*)(ws + 42467328);        // 25,165,824 B
    _Float16* O16    = xmm16;   // xmm16 dead after QKV GEMM; reuse for O

    prep_all<<<12864, 256, 0, stream>>>(xmm, xv, xa, Wq, Wkv, Wproj,
                                        xmm16, xsrc16, WqT, WkvT, WprojT);

    gemm_qkv<<<1152, 256, 0, stream>>>(xmm16, xsrc16, WqT, WkvT, Q16, KV16);

    attn_kernel<<<1536, 256, 0, stream>>>(Q16, KV16, attn, O16);

    gemm_proj<<<384, 256, 0, stream>>>(O16, WprojT, out, bproj);
}